// Round 1
// baseline (982.269 us; speedup 1.0000x reference)
//
#include <hip/hip_runtime.h>

// ---------------------------------------------------------------------------
// IAGNN: h=relu(x@W_in+b); 4x { gate=sig(a_s[src]+a_d[dst]+ba); m=h@Wm+bm;
//   agg=seg_sum(gate*m[src],dst); pre=agg+h@Wr+br; h=relu(featnorm(pre)) };
//   pooled=seg_sum(h,batch); logits=(relu(pooled@W1+b1)@W2+b2)/2
// Strategy: bf16 MFMA 16x16x32 for all big GEMMs (B in LDS, +8 bf16 pad ->
// 2-way bank alias = free), CSR-by-dst built per call (no fp32 scatter
// atomics), norm stats fused into aggregation, h/m stored bf16.
// ---------------------------------------------------------------------------

typedef __attribute__((ext_vector_type(8))) short short8;
typedef __attribute__((ext_vector_type(4))) float f32x4;

#define HDIM 128
#define NCOL_L 272      // 128 (Wm) + 128 (Wr) + 2 (Wa) + 14 pad -> 17 n-tiles
#define LDSTRIDE 136    // +8 bf16 pad: ncol stride 272B -> 2-way bank alias (free)
#define EPSN 1e-5f

__device__ __forceinline__ ushort f2bf(float f) {
    uint u = __float_as_uint(f);
    u += 0x7FFFu + ((u >> 16) & 1u);   // RNE
    return (ushort)(u >> 16);
}
__device__ __forceinline__ float bf2f(ushort b) {
    return __uint_as_float(((uint)b) << 16);
}
__device__ __forceinline__ f32x4 mfma_bf16(short8 a, short8 b, f32x4 c) {
    return __builtin_amdgcn_mfma_f32_16x16x32_bf16(a, b, c, 0, 0, 0);
}

// --------------------- weight prep: build B^T (bf16) -----------------------
// Btin[n][k] = W_in[k][n];  Btl[l][n][k]: n<128 Wm, n<256 Wr, 256/257 Wa, pad 0
__global__ void k_prep(const float* __restrict__ W_in, const float* __restrict__ Wa,
                       const float* __restrict__ Wm, const float* __restrict__ Wr,
                       ushort* __restrict__ Btin, ushort* __restrict__ Btl)
{
    int idx = blockIdx.x * 256 + threadIdx.x;
    if (idx < 128 * 128) {
        int n = idx >> 7, k = idx & 127;
        Btin[n * 128 + k] = f2bf(W_in[k * 128 + n]);
    } else {
        int j = idx - 128 * 128;
        int l = j / (NCOL_L * 128);
        int rem = j % (NCOL_L * 128);
        int n = rem >> 7, k = rem & 127;
        float v = 0.f;
        if (n < 128)        v = Wm[l * 16384 + k * 128 + n];
        else if (n < 256)   v = Wr[l * 16384 + k * 128 + (n - 128)];
        else if (n == 256)  v = Wa[l * 256 + k];
        else if (n == 257)  v = Wa[l * 256 + 128 + k];
        Btl[j] = f2bf(v);
    }
}

// --------------------------- CSR construction ------------------------------
__global__ void k_hist(const int* __restrict__ dst, int* __restrict__ counts, int E) {
    int e = blockIdx.x * 256 + threadIdx.x;
    if (e < E) atomicAdd(&counts[dst[e]], 1);
}

__global__ void k_scan1(const int* __restrict__ counts, int* __restrict__ offs,
                        int* __restrict__ bsums, int n) {
    __shared__ int sb[256];
    int tid = threadIdx.x;
    int i = blockIdx.x * 256 + tid;
    int v = (i < n) ? counts[i] : 0;
    sb[tid] = v; __syncthreads();
    for (int off = 1; off < 256; off <<= 1) {
        int t = (tid >= off) ? sb[tid - off] : 0;
        __syncthreads();
        sb[tid] += t;
        __syncthreads();
    }
    if (i < n) offs[i] = sb[tid] - v;           // exclusive within block
    if (tid == 255) bsums[blockIdx.x] = sb[255];
}

__global__ void k_scan2(int* __restrict__ bsums, int* __restrict__ offs, int nb, int n) {
    __shared__ int sb[256];
    int tid = threadIdx.x;
    int v = (tid < nb) ? bsums[tid] : 0;
    sb[tid] = v; __syncthreads();
    for (int off = 1; off < 256; off <<= 1) {
        int t = (tid >= off) ? sb[tid - off] : 0;
        __syncthreads();
        sb[tid] += t;
        __syncthreads();
    }
    if (tid < nb) bsums[tid] = sb[tid] - v;     // exclusive block offsets
    if (tid == 255) offs[n] = sb[255];          // total = E
}

__global__ void k_scan3(int* __restrict__ offs, const int* __restrict__ bsums, int n) {
    int i = blockIdx.x * 256 + threadIdx.x;
    if (i < n) offs[i] += bsums[blockIdx.x];
}

__global__ void k_bucket(const int* __restrict__ src, const int* __restrict__ dst,
                         const int* __restrict__ offs, int* __restrict__ cursor,
                         int* __restrict__ csrc, int E) {
    int e = blockIdx.x * 256 + threadIdx.x;
    if (e < E) {
        int d = dst[e];
        int slot = atomicAdd(&cursor[d], 1);
        csrc[offs[d] + slot] = src[e];
    }
}

// ------------------- input GEMM: h = relu(x @ W_in + b) --------------------
// block = 4 waves, 128 rows/block; wave: 32 rows (2 m-tiles) x 8 n-tiles
__global__ __launch_bounds__(256) void k_gemm_in(
    const float* __restrict__ X, const ushort* __restrict__ Bt,
    const float* __restrict__ bias, ushort* __restrict__ Hout, int M)
{
    __shared__ ushort Bs[128 * LDSTRIDE];
    int tid = threadIdx.x;
    for (int idx = tid; idx < 128 * 16; idx += 256) {
        int col = idx >> 4, kk = (idx & 15) << 3;
        uint4 v = *(const uint4*)(Bt + col * 128 + kk);
        *(uint4*)(&Bs[col * LDSTRIDE + kk]) = v;
    }
    int wave = tid >> 6, lane = tid & 63, quad = lane >> 4, l16 = lane & 15;
    int rowbase = blockIdx.x * 128 + wave * 32;
    short8 zf = {0,0,0,0,0,0,0,0};
    short8 afrag[2][4];
    for (int mt = 0; mt < 2; mt++) {
        int row = rowbase + mt * 16 + l16;
        if (row < M) {
            const float* ap = X + (size_t)row * 128;
            for (int kt = 0; kt < 4; kt++) {
                const float4* p = (const float4*)(ap + kt * 32 + quad * 8);
                float4 f0 = p[0], f1 = p[1];
                union { ushort us[8]; short8 v; } cv;
                cv.us[0]=f2bf(f0.x); cv.us[1]=f2bf(f0.y); cv.us[2]=f2bf(f0.z); cv.us[3]=f2bf(f0.w);
                cv.us[4]=f2bf(f1.x); cv.us[5]=f2bf(f1.y); cv.us[6]=f2bf(f1.z); cv.us[7]=f2bf(f1.w);
                afrag[mt][kt] = cv.v;
            }
        } else {
            for (int kt = 0; kt < 4; kt++) afrag[mt][kt] = zf;
        }
    }
    __syncthreads();
    for (int nt = 0; nt < 8; nt++) {
        f32x4 acc0 = {0.f,0.f,0.f,0.f}, acc1 = {0.f,0.f,0.f,0.f};
        for (int kt = 0; kt < 4; kt++) {
            short8 b = *(const short8*)(&Bs[(nt * 16 + l16) * LDSTRIDE + kt * 32 + quad * 8]);
            acc0 = mfma_bf16(afrag[0][kt], b, acc0);
            acc1 = mfma_bf16(afrag[1][kt], b, acc1);
        }
        int colg = nt * 16 + l16;
        float bv = bias[colg];
        for (int r = 0; r < 4; r++) {
            int row0 = rowbase + quad * 4 + r;
            if (row0 < M) {
                float v = acc0[r] + bv; v = v > 0.f ? v : 0.f;
                Hout[(size_t)row0 * 128 + colg] = f2bf(v);
            }
            int row1 = rowbase + 16 + quad * 4 + r;
            if (row1 < M) {
                float v = acc1[r] + bv; v = v > 0.f ? v : 0.f;
                Hout[(size_t)row1 * 128 + colg] = f2bf(v);
            }
        }
    }
}

// ---- layer GEMM: [m | r | a_src | a_dst] = h @ [Wm | Wr | Wa_s | Wa_d] ----
__global__ __launch_bounds__(256) void k_gemm_layer(
    const ushort* __restrict__ Hin, const ushort* __restrict__ Bt,
    const float* __restrict__ bm, const float* __restrict__ br,
    ushort* __restrict__ Mout, float* __restrict__ Rout,
    float* __restrict__ asrc, float* __restrict__ adst, int M)
{
    __shared__ ushort Bs[NCOL_L * LDSTRIDE];
    int tid = threadIdx.x;
    for (int idx = tid; idx < NCOL_L * 16; idx += 256) {
        int col = idx >> 4, kk = (idx & 15) << 3;
        uint4 v = *(const uint4*)(Bt + col * 128 + kk);
        *(uint4*)(&Bs[col * LDSTRIDE + kk]) = v;
    }
    int wave = tid >> 6, lane = tid & 63, quad = lane >> 4, l16 = lane & 15;
    int rowbase = blockIdx.x * 128 + wave * 32;
    short8 zf = {0,0,0,0,0,0,0,0};
    short8 afrag[2][4];
    for (int mt = 0; mt < 2; mt++) {
        int row = rowbase + mt * 16 + l16;
        for (int kt = 0; kt < 4; kt++) {
            afrag[mt][kt] = (row < M)
                ? *(const short8*)(Hin + (size_t)row * 128 + kt * 32 + quad * 8) : zf;
        }
    }
    __syncthreads();
    for (int nt = 0; nt < 17; nt++) {
        f32x4 acc0 = {0.f,0.f,0.f,0.f}, acc1 = {0.f,0.f,0.f,0.f};
        for (int kt = 0; kt < 4; kt++) {
            short8 b = *(const short8*)(&Bs[(nt * 16 + l16) * LDSTRIDE + kt * 32 + quad * 8]);
            acc0 = mfma_bf16(afrag[0][kt], b, acc0);
            acc1 = mfma_bf16(afrag[1][kt], b, acc1);
        }
        int colg = nt * 16 + l16;
        for (int half = 0; half < 2; half++) {
            f32x4 acc = half ? acc1 : acc0;
            int rb = rowbase + half * 16 + quad * 4;
            for (int r = 0; r < 4; r++) {
                int row = rb + r;
                if (row >= M) continue;
                float v = acc[r];
                if (colg < 128) {
                    Mout[(size_t)row * 128 + colg] = f2bf(v + bm[colg]);
                } else if (colg < 256) {
                    Rout[(size_t)row * 128 + (colg - 128)] = v + br[colg - 128];
                } else if (colg == 256) {
                    asrc[row] = v;
                } else if (colg == 257) {
                    adst[row] = v;
                }
            }
        }
    }
}

// ------ aggregation: pre = seg_sum(gate*m[src]) + r (in place) + stats -----
// wave per 4 nodes sequentially; lane covers feats [2*lane, 2*lane+1]
__global__ __launch_bounds__(256) void k_agg(
    const int* __restrict__ offs, const int* __restrict__ csrc,
    const float* __restrict__ asrc, const float* __restrict__ adst,
    const float* __restrict__ ba, const ushort* __restrict__ Mb,
    float* __restrict__ pre, float* __restrict__ stats, int Nn)
{
    __shared__ float s_acc[256];   // [0..127] sum, [128..255] sumsq per feature
    int tid = threadIdx.x;
    s_acc[tid] = 0.f;
    __syncthreads();
    int wave = tid >> 6, lane = tid & 63;
    float bav = ba[0];
    float ps0 = 0, ps1 = 0, pq0 = 0, pq1 = 0;
    for (int ni = 0; ni < 4; ni++) {
        int node = blockIdx.x * 16 + wave * 4 + ni;
        if (node >= Nn) break;
        int j0 = offs[node], j1 = offs[node + 1];
        float ad = adst[node];
        float a0 = 0.f, a1 = 0.f;
        for (int j = j0; j < j1; j++) {
            int s = csrc[j];
            float g = asrc[s] + ad + bav;
            g = 1.f / (1.f + __expf(-g));
            uint mm = *(const uint*)(Mb + (size_t)s * 128 + lane * 2);
            a0 += g * bf2f((ushort)(mm & 0xffffu));
            a1 += g * bf2f((ushort)(mm >> 16));
        }
        float2 rv = *(float2*)(pre + (size_t)node * 128 + lane * 2);
        float p0 = a0 + rv.x, p1 = a1 + rv.y;
        *(float2*)(pre + (size_t)node * 128 + lane * 2) = make_float2(p0, p1);
        ps0 += p0; ps1 += p1; pq0 += p0 * p0; pq1 += p1 * p1;
    }
    atomicAdd(&s_acc[lane * 2], ps0);
    atomicAdd(&s_acc[lane * 2 + 1], ps1);
    atomicAdd(&s_acc[128 + lane * 2], pq0);
    atomicAdd(&s_acc[128 + lane * 2 + 1], pq1);
    __syncthreads();
    atomicAdd(&stats[tid], s_acc[tid]);
}

// --------- norm: h = relu((pre-mu)*rsqrt(var+eps)*gamma+beta) -> bf16 ------
__global__ __launch_bounds__(256) void k_norm(
    const float* __restrict__ pre, const float* __restrict__ stats,
    const float* __restrict__ gamma, const float* __restrict__ beta,
    ushort* __restrict__ Hout, int Nn)
{
    int idx = blockIdx.x * 256 + threadIdx.x;   // one float4 group
    int row = idx >> 5;
    int f = (idx & 31) << 2;
    if (row >= Nn) return;
    float invN = 1.f / (float)Nn;
    float4 p = *(const float4*)(pre + (size_t)row * 128 + f);
    float vs[4] = {p.x, p.y, p.z, p.w};
    ushort os[4];
    for (int c = 0; c < 4; c++) {
        int fc = f + c;
        float mu = stats[fc] * invN;
        float var = stats[128 + fc] * invN - mu * mu;
        float rs = rsqrtf(var + EPSN);
        float v = (vs[c] - mu) * rs * gamma[fc] + beta[fc];
        v = v > 0.f ? v : 0.f;
        os[c] = f2bf(v);
    }
    uint2 st;
    st.x = (uint)os[0] | ((uint)os[1] << 16);
    st.y = (uint)os[2] | ((uint)os[3] << 16);
    *(uint2*)(Hout + (size_t)row * 128 + f) = st;
}

// --------------------- pool: pooled[g][f] += h[n][f] -----------------------
__global__ __launch_bounds__(128) void k_pool(
    const ushort* __restrict__ Hb, const int* __restrict__ batch,
    float* __restrict__ pooled, int Nn)
{
    int f = threadIdx.x;
    int n0 = blockIdx.x * 512;
    int n1 = n0 + 512; if (n1 > Nn) n1 = Nn;
    if (n0 >= n1) return;
    int curg = batch[n0];
    float acc = 0.f;
    for (int n = n0; n < n1; n++) {
        int g = batch[n];                  // sorted -> long runs, few flushes
        if (g != curg) { atomicAdd(&pooled[curg * 128 + f], acc); acc = 0.f; curg = g; }
        acc += bf2f(Hb[(size_t)n * 128 + f]);
    }
    atomicAdd(&pooled[curg * 128 + f], acc);
}

// ------------------------------ MLP head -----------------------------------
__global__ __launch_bounds__(256) void k_mlp(
    const float* __restrict__ pooled, const float* __restrict__ W1, const float* __restrict__ b1,
    const float* __restrict__ W2, const float* __restrict__ b2, float* __restrict__ out)
{
    __shared__ float P[64 * 128];
    __shared__ float Hd[64 * 64];
    int tid = threadIdx.x;
    for (int i = tid; i < 64 * 128; i += 256) P[i] = pooled[i];
    __syncthreads();
    for (int i = tid; i < 64 * 64; i += 256) {
        int g = i >> 6, j = i & 63;
        float s = b1[j];
        const float* pr = &P[g * 128];
        for (int k = 0; k < 128; k++) s += pr[k] * W1[k * 64 + j];
        Hd[i] = s > 0.f ? s : 0.f;
    }
    __syncthreads();
    for (int i = tid; i < 640; i += 256) {
        int g = i / 10, j = i % 10;
        float s = b2[j];
        const float* hr = &Hd[g * 64];
        for (int k = 0; k < 64; k++) s += hr[k] * W2[k * 10 + j];
        out[i] = s * 0.5f;   // / TEMP
    }
}

// ---------------------------------------------------------------------------
extern "C" void kernel_launch(void* const* d_in, const int* in_sizes, int n_in,
                              void* d_out, int out_size, void* d_ws, size_t ws_size,
                              hipStream_t stream)
{
    const float* x     = (const float*)d_in[0];
    const int*   ei    = (const int*)  d_in[1];
    const int*   batch = (const int*)  d_in[2];
    const float* W_in  = (const float*)d_in[3];
    const float* b_in  = (const float*)d_in[4];
    const float* Wa    = (const float*)d_in[5];
    const float* ba    = (const float*)d_in[6];
    const float* Wm    = (const float*)d_in[7];
    const float* bm    = (const float*)d_in[8];
    const float* Wr    = (const float*)d_in[9];
    const float* br    = (const float*)d_in[10];
    const float* gamma = (const float*)d_in[11];
    const float* beta  = (const float*)d_in[12];
    const float* W1    = (const float*)d_in[13];
    const float* b1    = (const float*)d_in[14];
    const float* W2    = (const float*)d_in[15];
    const float* b2    = (const float*)d_in[16];
    float* out = (float*)d_out;

    const int N = in_sizes[0] / 128;    // 50000
    const int E = in_sizes[1] / 2;      // 600000
    const int* e_src = ei;
    const int* e_dst = ei + E;

    // -------- workspace layout (bytes) --------
    char* ws = (char*)d_ws;
    ushort* h_b    = (ushort*)(ws + 0);               // 12,800,000  bf16 h
    ushort* m_b    = (ushort*)(ws + 12800000);        // 12,800,000  bf16 m
    float*  pre    = (float*) (ws + 25600000);        // 25,600,000  r/pre fp32
    float*  asrc   = (float*) (ws + 51200000);        //    200,000
    float*  adst   = (float*) (ws + 51400000);        //    200,000
    int*    counts = (int*)   (ws + 51600000);        //    200,000
    int*    cursor = (int*)   (ws + 51800000);        //    200,000
    int*    offs   = (int*)   (ws + 52000000);        //    200,064 (N+1)
    int*    csrc   = (int*)   (ws + 52200064);        //  2,400,000
    int*    bsums  = (int*)   (ws + 54600064);        //      1,024
    ushort* Btin   = (ushort*)(ws + 54601088);        //     32,768
    ushort* Btl    = (ushort*)(ws + 54633856);        //    278,528
    float*  stats  = (float*) (ws + 54912384);        //      4,096 (4 x 256)
    float*  pooled = (float*) (ws + 54916480);        //     32,768
    (void)ws_size; (void)n_in; (void)out_size;

    // zero accumulators (counts+cursor contiguous; stats+pooled contiguous)
    hipMemsetAsync(counts, 0, 400000, stream);
    hipMemsetAsync(stats, 0, 36864, stream);

    const int nbE = (E + 255) / 256;          // 2344
    const int nbN = (N + 255) / 256;          // 196
    const int nbG = (N + 127) / 128;          // 391 gemm blocks
    const int nbA = (N + 15) / 16;            // 3125 agg blocks
    const int nbNorm = (N * 32 + 255) / 256;  // 6250
    const int nbP = (N + 511) / 512;          // 98

    k_prep<<<608, 256, 0, stream>>>(W_in, Wa, Wm, Wr, Btin, Btl);
    k_hist<<<nbE, 256, 0, stream>>>(e_dst, counts, E);
    k_scan1<<<nbN, 256, 0, stream>>>(counts, offs, bsums, N);
    k_scan2<<<1, 256, 0, stream>>>(bsums, offs, nbN, N);
    k_scan3<<<nbN, 256, 0, stream>>>(offs, bsums, N);
    k_bucket<<<nbE, 256, 0, stream>>>(e_src, e_dst, offs, cursor, csrc, E);

    k_gemm_in<<<nbG, 256, 0, stream>>>(x, Btin, b_in, h_b, N);

    for (int l = 0; l < 4; l++) {
        k_gemm_layer<<<nbG, 256, 0, stream>>>(h_b, Btl + l * (NCOL_L * 128),
                                              bm + l * 128, br + l * 128,
                                              m_b, pre, asrc, adst, N);
        k_agg<<<nbA, 256, 0, stream>>>(offs, csrc, asrc, adst, ba + l,
                                       m_b, pre, stats + l * 256, N);
        k_norm<<<nbNorm, 256, 0, stream>>>(pre, stats + l * 256,
                                           gamma + l * 128, beta + l * 128, h_b, N);
    }

    k_pool<<<nbP, 128, 0, stream>>>(h_b, batch, pooled, N);
    k_mlp<<<1, 256, 0, stream>>>(pooled, W1, b1, W2, b2, out);
}

// Round 2
// 656.435 us; speedup vs baseline: 1.4964x; 1.4964x over previous
//
#include <hip/hip_runtime.h>

// ---------------------------------------------------------------------------
// IAGNN: h=relu(x@W_in+b); 4x { gate=sig(a_s[src]+a_d[dst]+ba); m=h@Wm+bm;
//   agg=seg_sum(gate*m[src],dst); pre=agg+h@Wr+br; h=relu(featnorm(pre)) };
//   pooled=seg_sum(h,batch); logits=(relu(pooled@W1+b1)@W2+b2)/2
// R2: k_pool -> group-boundary precompute + block-per-graph streaming reduce
//     (was 143us latency-bound); k_agg edge loop unroll-4 (8 loads in flight);
//     k_mlp block-per-graph.
// ---------------------------------------------------------------------------

typedef __attribute__((ext_vector_type(8))) short short8;
typedef __attribute__((ext_vector_type(4))) float f32x4;

#define HDIM 128
#define NCOL_L 272      // 128 (Wm) + 128 (Wr) + 2 (Wa) + 14 pad -> 17 n-tiles
#define LDSTRIDE 136    // +8 bf16 pad: 2-way bank alias (free per m136)
#define EPSN 1e-5f
#define NGRAPH 64

__device__ __forceinline__ ushort f2bf(float f) {
    uint u = __float_as_uint(f);
    u += 0x7FFFu + ((u >> 16) & 1u);   // RNE
    return (ushort)(u >> 16);
}
__device__ __forceinline__ float bf2f(ushort b) {
    return __uint_as_float(((uint)b) << 16);
}
__device__ __forceinline__ float bflo(uint u) { return __uint_as_float(u << 16); }
__device__ __forceinline__ float bfhi(uint u) { return __uint_as_float(u & 0xffff0000u); }
__device__ __forceinline__ f32x4 mfma_bf16(short8 a, short8 b, f32x4 c) {
    return __builtin_amdgcn_mfma_f32_16x16x32_bf16(a, b, c, 0, 0, 0);
}

// --------------------- weight prep: build B^T (bf16) -----------------------
__global__ void k_prep(const float* __restrict__ W_in, const float* __restrict__ Wa,
                       const float* __restrict__ Wm, const float* __restrict__ Wr,
                       ushort* __restrict__ Btin, ushort* __restrict__ Btl)
{
    int idx = blockIdx.x * 256 + threadIdx.x;
    if (idx < 128 * 128) {
        int n = idx >> 7, k = idx & 127;
        Btin[n * 128 + k] = f2bf(W_in[k * 128 + n]);
    } else {
        int j = idx - 128 * 128;
        int l = j / (NCOL_L * 128);
        int rem = j % (NCOL_L * 128);
        int n = rem >> 7, k = rem & 127;
        float v = 0.f;
        if (n < 128)        v = Wm[l * 16384 + k * 128 + n];
        else if (n < 256)   v = Wr[l * 16384 + k * 128 + (n - 128)];
        else if (n == 256)  v = Wa[l * 256 + k];
        else if (n == 257)  v = Wa[l * 256 + 128 + k];
        Btl[j] = f2bf(v);
    }
}

// --------------------------- CSR construction ------------------------------
__global__ void k_hist(const int* __restrict__ dst, int* __restrict__ counts, int E) {
    int e = blockIdx.x * 256 + threadIdx.x;
    if (e < E) atomicAdd(&counts[dst[e]], 1);
}

__global__ void k_scan1(const int* __restrict__ counts, int* __restrict__ offs,
                        int* __restrict__ bsums, int n) {
    __shared__ int sb[256];
    int tid = threadIdx.x;
    int i = blockIdx.x * 256 + tid;
    int v = (i < n) ? counts[i] : 0;
    sb[tid] = v; __syncthreads();
    for (int off = 1; off < 256; off <<= 1) {
        int t = (tid >= off) ? sb[tid - off] : 0;
        __syncthreads();
        sb[tid] += t;
        __syncthreads();
    }
    if (i < n) offs[i] = sb[tid] - v;
    if (tid == 255) bsums[blockIdx.x] = sb[255];
}

__global__ void k_scan2(int* __restrict__ bsums, int* __restrict__ offs, int nb, int n) {
    __shared__ int sb[256];
    int tid = threadIdx.x;
    int v = (tid < nb) ? bsums[tid] : 0;
    sb[tid] = v; __syncthreads();
    for (int off = 1; off < 256; off <<= 1) {
        int t = (tid >= off) ? sb[tid - off] : 0;
        __syncthreads();
        sb[tid] += t;
        __syncthreads();
    }
    if (tid < nb) bsums[tid] = sb[tid] - v;
    if (tid == 255) offs[n] = sb[255];
}

__global__ void k_scan3(int* __restrict__ offs, const int* __restrict__ bsums, int n) {
    int i = blockIdx.x * 256 + threadIdx.x;
    if (i < n) offs[i] += bsums[blockIdx.x];
}

__global__ void k_bucket(const int* __restrict__ src, const int* __restrict__ dst,
                         const int* __restrict__ offs, int* __restrict__ cursor,
                         int* __restrict__ csrc, int E) {
    int e = blockIdx.x * 256 + threadIdx.x;
    if (e < E) {
        int d = dst[e];
        int slot = atomicAdd(&cursor[d], 1);
        csrc[offs[d] + slot] = src[e];
    }
}

// ---------------- group boundaries from sorted batch vector ----------------
__global__ void k_gbound(const int* __restrict__ batch, int* __restrict__ gstart, int Nn) {
    int n = blockIdx.x * 256 + threadIdx.x;
    if (n >= Nn) return;
    int b = batch[n];
    int prev = (n == 0) ? -1 : batch[n - 1];
    for (int g = prev + 1; g <= b; g++) gstart[g] = n;
    if (n == Nn - 1) for (int g = b + 1; g <= NGRAPH; g++) gstart[g] = Nn;
}

// ------------------- input GEMM: h = relu(x @ W_in + b) --------------------
__global__ __launch_bounds__(256) void k_gemm_in(
    const float* __restrict__ X, const ushort* __restrict__ Bt,
    const float* __restrict__ bias, ushort* __restrict__ Hout, int M)
{
    __shared__ ushort Bs[128 * LDSTRIDE];
    int tid = threadIdx.x;
    for (int idx = tid; idx < 128 * 16; idx += 256) {
        int col = idx >> 4, kk = (idx & 15) << 3;
        uint4 v = *(const uint4*)(Bt + col * 128 + kk);
        *(uint4*)(&Bs[col * LDSTRIDE + kk]) = v;
    }
    int wave = tid >> 6, lane = tid & 63, quad = lane >> 4, l16 = lane & 15;
    int rowbase = blockIdx.x * 128 + wave * 32;
    short8 zf = {0,0,0,0,0,0,0,0};
    short8 afrag[2][4];
    for (int mt = 0; mt < 2; mt++) {
        int row = rowbase + mt * 16 + l16;
        if (row < M) {
            const float* ap = X + (size_t)row * 128;
            for (int kt = 0; kt < 4; kt++) {
                const float4* p = (const float4*)(ap + kt * 32 + quad * 8);
                float4 f0 = p[0], f1 = p[1];
                union { ushort us[8]; short8 v; } cv;
                cv.us[0]=f2bf(f0.x); cv.us[1]=f2bf(f0.y); cv.us[2]=f2bf(f0.z); cv.us[3]=f2bf(f0.w);
                cv.us[4]=f2bf(f1.x); cv.us[5]=f2bf(f1.y); cv.us[6]=f2bf(f1.z); cv.us[7]=f2bf(f1.w);
                afrag[mt][kt] = cv.v;
            }
        } else {
            for (int kt = 0; kt < 4; kt++) afrag[mt][kt] = zf;
        }
    }
    __syncthreads();
    for (int nt = 0; nt < 8; nt++) {
        f32x4 acc0 = {0.f,0.f,0.f,0.f}, acc1 = {0.f,0.f,0.f,0.f};
        for (int kt = 0; kt < 4; kt++) {
            short8 b = *(const short8*)(&Bs[(nt * 16 + l16) * LDSTRIDE + kt * 32 + quad * 8]);
            acc0 = mfma_bf16(afrag[0][kt], b, acc0);
            acc1 = mfma_bf16(afrag[1][kt], b, acc1);
        }
        int colg = nt * 16 + l16;
        float bv = bias[colg];
        for (int r = 0; r < 4; r++) {
            int row0 = rowbase + quad * 4 + r;
            if (row0 < M) {
                float v = acc0[r] + bv; v = v > 0.f ? v : 0.f;
                Hout[(size_t)row0 * 128 + colg] = f2bf(v);
            }
            int row1 = rowbase + 16 + quad * 4 + r;
            if (row1 < M) {
                float v = acc1[r] + bv; v = v > 0.f ? v : 0.f;
                Hout[(size_t)row1 * 128 + colg] = f2bf(v);
            }
        }
    }
}

// ---- layer GEMM: [m | r | a_src | a_dst] = h @ [Wm | Wr | Wa_s | Wa_d] ----
__global__ __launch_bounds__(256) void k_gemm_layer(
    const ushort* __restrict__ Hin, const ushort* __restrict__ Bt,
    const float* __restrict__ bm, const float* __restrict__ br,
    ushort* __restrict__ Mout, float* __restrict__ Rout,
    float* __restrict__ asrc, float* __restrict__ adst, int M)
{
    __shared__ ushort Bs[NCOL_L * LDSTRIDE];
    int tid = threadIdx.x;
    for (int idx = tid; idx < NCOL_L * 16; idx += 256) {
        int col = idx >> 4, kk = (idx & 15) << 3;
        uint4 v = *(const uint4*)(Bt + col * 128 + kk);
        *(uint4*)(&Bs[col * LDSTRIDE + kk]) = v;
    }
    int wave = tid >> 6, lane = tid & 63, quad = lane >> 4, l16 = lane & 15;
    int rowbase = blockIdx.x * 128 + wave * 32;
    short8 zf = {0,0,0,0,0,0,0,0};
    short8 afrag[2][4];
    for (int mt = 0; mt < 2; mt++) {
        int row = rowbase + mt * 16 + l16;
        for (int kt = 0; kt < 4; kt++) {
            afrag[mt][kt] = (row < M)
                ? *(const short8*)(Hin + (size_t)row * 128 + kt * 32 + quad * 8) : zf;
        }
    }
    __syncthreads();
    for (int nt = 0; nt < 17; nt++) {
        f32x4 acc0 = {0.f,0.f,0.f,0.f}, acc1 = {0.f,0.f,0.f,0.f};
        for (int kt = 0; kt < 4; kt++) {
            short8 b = *(const short8*)(&Bs[(nt * 16 + l16) * LDSTRIDE + kt * 32 + quad * 8]);
            acc0 = mfma_bf16(afrag[0][kt], b, acc0);
            acc1 = mfma_bf16(afrag[1][kt], b, acc1);
        }
        int colg = nt * 16 + l16;
        for (int half = 0; half < 2; half++) {
            f32x4 acc = half ? acc1 : acc0;
            int rb = rowbase + half * 16 + quad * 4;
            for (int r = 0; r < 4; r++) {
                int row = rb + r;
                if (row >= M) continue;
                float v = acc[r];
                if (colg < 128) {
                    Mout[(size_t)row * 128 + colg] = f2bf(v + bm[colg]);
                } else if (colg < 256) {
                    Rout[(size_t)row * 128 + (colg - 128)] = v + br[colg - 128];
                } else if (colg == 256) {
                    asrc[row] = v;
                } else if (colg == 257) {
                    adst[row] = v;
                }
            }
        }
    }
}

// ------ aggregation: pre = seg_sum(gate*m[src]) + r (in place) + stats -----
// block = 4 waves x 8 nodes; lane covers feats [2*lane, 2*lane+1]; edge loop
// unrolled x4 -> 8 independent loads in flight per group.
__global__ __launch_bounds__(256) void k_agg(
    const int* __restrict__ offs, const int* __restrict__ csrc,
    const float* __restrict__ asrc, const float* __restrict__ adst,
    const float* __restrict__ ba, const ushort* __restrict__ Mb,
    float* __restrict__ pre, float* __restrict__ stats, int Nn)
{
    __shared__ float s_acc[256];   // [0..127] sum, [128..255] sumsq per feature
    int tid = threadIdx.x;
    s_acc[tid] = 0.f;
    __syncthreads();
    int wave = tid >> 6, lane = tid & 63;
    float bav = ba[0];
    float ps0 = 0, ps1 = 0, pq0 = 0, pq1 = 0;
    for (int ni = 0; ni < 8; ni++) {
        int node = blockIdx.x * 32 + wave * 8 + ni;
        if (node >= Nn) break;
        int j0 = offs[node], j1 = offs[node + 1];
        float ad = adst[node] + bav;
        float a0 = 0.f, a1 = 0.f;
        int j = j0;
        for (; j + 4 <= j1; j += 4) {
            int s0 = csrc[j], s1 = csrc[j+1], s2 = csrc[j+2], s3 = csrc[j+3];
            float as0 = asrc[s0], as1 = asrc[s1], as2 = asrc[s2], as3 = asrc[s3];
            uint m0 = *(const uint*)(Mb + (size_t)s0 * 128 + lane * 2);
            uint m1 = *(const uint*)(Mb + (size_t)s1 * 128 + lane * 2);
            uint m2 = *(const uint*)(Mb + (size_t)s2 * 128 + lane * 2);
            uint m3 = *(const uint*)(Mb + (size_t)s3 * 128 + lane * 2);
            float g0 = 1.f / (1.f + __expf(-(as0 + ad)));
            float g1 = 1.f / (1.f + __expf(-(as1 + ad)));
            float g2 = 1.f / (1.f + __expf(-(as2 + ad)));
            float g3 = 1.f / (1.f + __expf(-(as3 + ad)));
            a0 += g0 * bflo(m0) + g1 * bflo(m1) + g2 * bflo(m2) + g3 * bflo(m3);
            a1 += g0 * bfhi(m0) + g1 * bfhi(m1) + g2 * bfhi(m2) + g3 * bfhi(m3);
        }
        for (; j < j1; j++) {
            int s = csrc[j];
            float g = 1.f / (1.f + __expf(-(asrc[s] + ad)));
            uint mm = *(const uint*)(Mb + (size_t)s * 128 + lane * 2);
            a0 += g * bflo(mm);
            a1 += g * bfhi(mm);
        }
        float2 rv = *(float2*)(pre + (size_t)node * 128 + lane * 2);
        float p0 = a0 + rv.x, p1 = a1 + rv.y;
        *(float2*)(pre + (size_t)node * 128 + lane * 2) = make_float2(p0, p1);
        ps0 += p0; ps1 += p1; pq0 += p0 * p0; pq1 += p1 * p1;
    }
    atomicAdd(&s_acc[lane * 2], ps0);
    atomicAdd(&s_acc[lane * 2 + 1], ps1);
    atomicAdd(&s_acc[128 + lane * 2], pq0);
    atomicAdd(&s_acc[128 + lane * 2 + 1], pq1);
    __syncthreads();
    atomicAdd(&stats[tid], s_acc[tid]);
}

// --------- norm: h = relu((pre-mu)*rsqrt(var+eps)*gamma+beta) -> bf16 ------
__global__ __launch_bounds__(256) void k_norm(
    const float* __restrict__ pre, const float* __restrict__ stats,
    const float* __restrict__ gamma, const float* __restrict__ beta,
    ushort* __restrict__ Hout, int Nn)
{
    int idx = blockIdx.x * 256 + threadIdx.x;
    int row = idx >> 5;
    int f = (idx & 31) << 2;
    if (row >= Nn) return;
    float invN = 1.f / (float)Nn;
    float4 p = *(const float4*)(pre + (size_t)row * 128 + f);
    float vs[4] = {p.x, p.y, p.z, p.w};
    ushort os[4];
    for (int c = 0; c < 4; c++) {
        int fc = f + c;
        float mu = stats[fc] * invN;
        float var = stats[128 + fc] * invN - mu * mu;
        float rs = rsqrtf(var + EPSN);
        float v = (vs[c] - mu) * rs * gamma[fc] + beta[fc];
        v = v > 0.f ? v : 0.f;
        os[c] = f2bf(v);
    }
    uint2 st;
    st.x = (uint)os[0] | ((uint)os[1] << 16);
    st.y = (uint)os[2] | ((uint)os[3] << 16);
    *(uint2*)(Hout + (size_t)row * 128 + f) = st;
}

// ---------- pool: block per graph, 4 waves stride rows, LDS reduce ---------
__global__ __launch_bounds__(256) void k_pool(
    const ushort* __restrict__ Hb, const int* __restrict__ gstart,
    float* __restrict__ pooled)
{
    __shared__ float sred[512];
    int g = blockIdx.x;
    int n0 = gstart[g], n1 = gstart[g + 1];
    int wave = threadIdx.x >> 6, lane = threadIdx.x & 63;
    float a0 = 0.f, a1 = 0.f;
    int n = n0 + wave;
    // 4 independent row loads in flight per wave
    for (; n + 12 < n1; n += 16) {
        uint u0 = *(const uint*)(Hb + (size_t)n * 128 + lane * 2);
        uint u1 = *(const uint*)(Hb + (size_t)(n + 4) * 128 + lane * 2);
        uint u2 = *(const uint*)(Hb + (size_t)(n + 8) * 128 + lane * 2);
        uint u3 = *(const uint*)(Hb + (size_t)(n + 12) * 128 + lane * 2);
        a0 += bflo(u0) + bflo(u1) + bflo(u2) + bflo(u3);
        a1 += bfhi(u0) + bfhi(u1) + bfhi(u2) + bfhi(u3);
    }
    for (; n < n1; n += 4) {
        uint u = *(const uint*)(Hb + (size_t)n * 128 + lane * 2);
        a0 += bflo(u);
        a1 += bfhi(u);
    }
    sred[wave * 128 + lane * 2]     = a0;
    sred[wave * 128 + lane * 2 + 1] = a1;
    __syncthreads();
    if (threadIdx.x < 128) {
        float s = sred[threadIdx.x] + sred[128 + threadIdx.x]
                + sred[256 + threadIdx.x] + sred[384 + threadIdx.x];
        pooled[g * 128 + threadIdx.x] = s;
    }
}

// ----------------------- MLP head: block per graph -------------------------
__global__ __launch_bounds__(64) void k_mlp(
    const float* __restrict__ pooled, const float* __restrict__ W1, const float* __restrict__ b1,
    const float* __restrict__ W2, const float* __restrict__ b2, float* __restrict__ out)
{
    __shared__ float P[128];
    __shared__ float Hd[64];
    int g = blockIdx.x, j = threadIdx.x;
    P[j] = pooled[g * 128 + j];
    P[j + 64] = pooled[g * 128 + 64 + j];
    __syncthreads();
    float s0 = 0.f, s1 = 0.f, s2 = 0.f, s3 = 0.f;
    for (int k = 0; k < 128; k += 4) {
        s0 += P[k]     * W1[k * 64 + j];
        s1 += P[k + 1] * W1[(k + 1) * 64 + j];
        s2 += P[k + 2] * W1[(k + 2) * 64 + j];
        s3 += P[k + 3] * W1[(k + 3) * 64 + j];
    }
    float s = b1[j] + ((s0 + s1) + (s2 + s3));
    Hd[j] = s > 0.f ? s : 0.f;
    __syncthreads();
    if (j < 10) {
        float t0 = 0.f, t1 = 0.f;
        for (int k = 0; k < 64; k += 2) {
            t0 += Hd[k]     * W2[k * 10 + j];
            t1 += Hd[k + 1] * W2[(k + 1) * 10 + j];
        }
        out[g * 10 + j] = (b2[j] + t0 + t1) * 0.5f;   // / TEMP
    }
}

// ---------------------------------------------------------------------------
extern "C" void kernel_launch(void* const* d_in, const int* in_sizes, int n_in,
                              void* d_out, int out_size, void* d_ws, size_t ws_size,
                              hipStream_t stream)
{
    const float* x     = (const float*)d_in[0];
    const int*   ei    = (const int*)  d_in[1];
    const int*   batch = (const int*)  d_in[2];
    const float* W_in  = (const float*)d_in[3];
    const float* b_in  = (const float*)d_in[4];
    const float* Wa    = (const float*)d_in[5];
    const float* ba    = (const float*)d_in[6];
    const float* Wm    = (const float*)d_in[7];
    const float* bm    = (const float*)d_in[8];
    const float* Wr    = (const float*)d_in[9];
    const float* br    = (const float*)d_in[10];
    const float* gamma = (const float*)d_in[11];
    const float* beta  = (const float*)d_in[12];
    const float* W1    = (const float*)d_in[13];
    const float* b1    = (const float*)d_in[14];
    const float* W2    = (const float*)d_in[15];
    const float* b2    = (const float*)d_in[16];
    float* out = (float*)d_out;

    const int N = in_sizes[0] / 128;    // 50000
    const int E = in_sizes[1] / 2;      // 600000
    const int* e_src = ei;
    const int* e_dst = ei + E;

    // -------- workspace layout (bytes) --------
    char* ws = (char*)d_ws;
    ushort* h_b    = (ushort*)(ws + 0);               // 12,800,000  bf16 h
    ushort* m_b    = (ushort*)(ws + 12800000);        // 12,800,000  bf16 m
    float*  pre    = (float*) (ws + 25600000);        // 25,600,000  r/pre fp32
    float*  asrc   = (float*) (ws + 51200000);        //    200,000
    float*  adst   = (float*) (ws + 51400000);        //    200,000
    int*    counts = (int*)   (ws + 51600000);        //    200,000
    int*    cursor = (int*)   (ws + 51800000);        //    200,000
    int*    offs   = (int*)   (ws + 52000000);        //    200,064 (N+1)
    int*    csrc   = (int*)   (ws + 52200064);        //  2,400,000
    int*    bsums  = (int*)   (ws + 54600064);        //      1,024
    ushort* Btin   = (ushort*)(ws + 54601088);        //     32,768
    ushort* Btl    = (ushort*)(ws + 54633856);        //    278,528
    float*  stats  = (float*) (ws + 54912384);        //      4,096 (4 x 256)
    float*  pooled = (float*) (ws + 54916480);        //     32,768
    int*    gstart = (int*)   (ws + 54949248);        //        260 (G+1)
    (void)ws_size; (void)n_in; (void)out_size;

    hipMemsetAsync(counts, 0, 400000, stream);   // counts + cursor
    hipMemsetAsync(stats, 0, 4096, stream);      // stats only (pooled written direct)

    const int nbE = (E + 255) / 256;          // 2344
    const int nbN = (N + 255) / 256;          // 196
    const int nbG = (N + 127) / 128;          // 391 gemm blocks
    const int nbA = (N + 31) / 32;            // 1563 agg blocks
    const int nbNorm = (N * 32 + 255) / 256;  // 6250

    k_prep<<<608, 256, 0, stream>>>(W_in, Wa, Wm, Wr, Btin, Btl);
    k_hist<<<nbE, 256, 0, stream>>>(e_dst, counts, E);
    k_scan1<<<nbN, 256, 0, stream>>>(counts, offs, bsums, N);
    k_scan2<<<1, 256, 0, stream>>>(bsums, offs, nbN, N);
    k_scan3<<<nbN, 256, 0, stream>>>(offs, bsums, N);
    k_bucket<<<nbE, 256, 0, stream>>>(e_src, e_dst, offs, cursor, csrc, E);
    k_gbound<<<nbN, 256, 0, stream>>>(batch, gstart, N);

    k_gemm_in<<<nbG, 256, 0, stream>>>(x, Btin, b_in, h_b, N);

    for (int l = 0; l < 4; l++) {
        k_gemm_layer<<<nbG, 256, 0, stream>>>(h_b, Btl + l * (NCOL_L * 128),
                                              bm + l * 128, br + l * 128,
                                              m_b, pre, asrc, adst, N);
        k_agg<<<nbA, 256, 0, stream>>>(offs, csrc, asrc, adst, ba + l,
                                       m_b, pre, stats + l * 256, N);
        k_norm<<<nbNorm, 256, 0, stream>>>(pre, stats + l * 256,
                                           gamma + l * 128, beta + l * 128, h_b, N);
    }

    k_pool<<<NGRAPH, 256, 0, stream>>>(h_b, gstart, pooled);
    k_mlp<<<NGRAPH, 64, 0, stream>>>(pooled, W1, b1, W2, b2, out);
}

// Round 3
// 621.633 us; speedup vs baseline: 1.5801x; 1.0560x over previous
//
#include <hip/hip_runtime.h>

// ---------------------------------------------------------------------------
// IAGNN: h=relu(x@W_in+b); 4x { gate=sig(a_s[src]+a_d[dst]+ba); m=h@Wm+bm;
//   agg=seg_sum(gate*m[src],dst); pre=agg+h@Wr+br; h=relu(featnorm(pre)) };
//   pooled=seg_sum(h,batch); logits=(relu(pooled@W1+b1)@W2+b2)/2
// R3: k_agg restructured -- lane-parallel edge setup (coalesced csrc load,
//   parallel asrc gather, parallel sigmoid) + __shfl broadcast of (s,g);
//   m-row loads fully independent -> latency chain cut from 2 serial loads
//   per edge-group to zero (indices in registers).
// ---------------------------------------------------------------------------

typedef __attribute__((ext_vector_type(8))) short short8;
typedef __attribute__((ext_vector_type(4))) float f32x4;

#define HDIM 128
#define NCOL_L 272      // 128 (Wm) + 128 (Wr) + 2 (Wa) + 14 pad -> 17 n-tiles
#define LDSTRIDE 136    // +8 bf16 pad: 2-way bank alias (free per m136)
#define EPSN 1e-5f
#define NGRAPH 64

__device__ __forceinline__ ushort f2bf(float f) {
    uint u = __float_as_uint(f);
    u += 0x7FFFu + ((u >> 16) & 1u);   // RNE
    return (ushort)(u >> 16);
}
__device__ __forceinline__ float bf2f(ushort b) {
    return __uint_as_float(((uint)b) << 16);
}
__device__ __forceinline__ float bflo(uint u) { return __uint_as_float(u << 16); }
__device__ __forceinline__ float bfhi(uint u) { return __uint_as_float(u & 0xffff0000u); }
__device__ __forceinline__ f32x4 mfma_bf16(short8 a, short8 b, f32x4 c) {
    return __builtin_amdgcn_mfma_f32_16x16x32_bf16(a, b, c, 0, 0, 0);
}

// --------------------- weight prep: build B^T (bf16) -----------------------
__global__ void k_prep(const float* __restrict__ W_in, const float* __restrict__ Wa,
                       const float* __restrict__ Wm, const float* __restrict__ Wr,
                       ushort* __restrict__ Btin, ushort* __restrict__ Btl)
{
    int idx = blockIdx.x * 256 + threadIdx.x;
    if (idx < 128 * 128) {
        int n = idx >> 7, k = idx & 127;
        Btin[n * 128 + k] = f2bf(W_in[k * 128 + n]);
    } else {
        int j = idx - 128 * 128;
        int l = j / (NCOL_L * 128);
        int rem = j % (NCOL_L * 128);
        int n = rem >> 7, k = rem & 127;
        float v = 0.f;
        if (n < 128)        v = Wm[l * 16384 + k * 128 + n];
        else if (n < 256)   v = Wr[l * 16384 + k * 128 + (n - 128)];
        else if (n == 256)  v = Wa[l * 256 + k];
        else if (n == 257)  v = Wa[l * 256 + 128 + k];
        Btl[j] = f2bf(v);
    }
}

// --------------------------- CSR construction ------------------------------
__global__ void k_hist(const int* __restrict__ dst, int* __restrict__ counts, int E) {
    int e = blockIdx.x * 256 + threadIdx.x;
    if (e < E) atomicAdd(&counts[dst[e]], 1);
}

__global__ void k_scan1(const int* __restrict__ counts, int* __restrict__ offs,
                        int* __restrict__ bsums, int n) {
    __shared__ int sb[256];
    int tid = threadIdx.x;
    int i = blockIdx.x * 256 + tid;
    int v = (i < n) ? counts[i] : 0;
    sb[tid] = v; __syncthreads();
    for (int off = 1; off < 256; off <<= 1) {
        int t = (tid >= off) ? sb[tid - off] : 0;
        __syncthreads();
        sb[tid] += t;
        __syncthreads();
    }
    if (i < n) offs[i] = sb[tid] - v;
    if (tid == 255) bsums[blockIdx.x] = sb[255];
}

__global__ void k_scan2(int* __restrict__ bsums, int* __restrict__ offs, int nb, int n) {
    __shared__ int sb[256];
    int tid = threadIdx.x;
    int v = (tid < nb) ? bsums[tid] : 0;
    sb[tid] = v; __syncthreads();
    for (int off = 1; off < 256; off <<= 1) {
        int t = (tid >= off) ? sb[tid - off] : 0;
        __syncthreads();
        sb[tid] += t;
        __syncthreads();
    }
    if (tid < nb) bsums[tid] = sb[tid] - v;
    if (tid == 255) offs[n] = sb[255];
}

__global__ void k_scan3(int* __restrict__ offs, const int* __restrict__ bsums, int n) {
    int i = blockIdx.x * 256 + threadIdx.x;
    if (i < n) offs[i] += bsums[blockIdx.x];
}

__global__ void k_bucket(const int* __restrict__ src, const int* __restrict__ dst,
                         const int* __restrict__ offs, int* __restrict__ cursor,
                         int* __restrict__ csrc, int E) {
    int e = blockIdx.x * 256 + threadIdx.x;
    if (e < E) {
        int d = dst[e];
        int slot = atomicAdd(&cursor[d], 1);
        csrc[offs[d] + slot] = src[e];
    }
}

// ---------------- group boundaries from sorted batch vector ----------------
__global__ void k_gbound(const int* __restrict__ batch, int* __restrict__ gstart, int Nn) {
    int n = blockIdx.x * 256 + threadIdx.x;
    if (n >= Nn) return;
    int b = batch[n];
    int prev = (n == 0) ? -1 : batch[n - 1];
    for (int g = prev + 1; g <= b; g++) gstart[g] = n;
    if (n == Nn - 1) for (int g = b + 1; g <= NGRAPH; g++) gstart[g] = Nn;
}

// ------------------- input GEMM: h = relu(x @ W_in + b) --------------------
__global__ __launch_bounds__(256) void k_gemm_in(
    const float* __restrict__ X, const ushort* __restrict__ Bt,
    const float* __restrict__ bias, ushort* __restrict__ Hout, int M)
{
    __shared__ ushort Bs[128 * LDSTRIDE];
    int tid = threadIdx.x;
    for (int idx = tid; idx < 128 * 16; idx += 256) {
        int col = idx >> 4, kk = (idx & 15) << 3;
        uint4 v = *(const uint4*)(Bt + col * 128 + kk);
        *(uint4*)(&Bs[col * LDSTRIDE + kk]) = v;
    }
    int wave = tid >> 6, lane = tid & 63, quad = lane >> 4, l16 = lane & 15;
    int rowbase = blockIdx.x * 128 + wave * 32;
    short8 zf = {0,0,0,0,0,0,0,0};
    short8 afrag[2][4];
    for (int mt = 0; mt < 2; mt++) {
        int row = rowbase + mt * 16 + l16;
        if (row < M) {
            const float* ap = X + (size_t)row * 128;
            for (int kt = 0; kt < 4; kt++) {
                const float4* p = (const float4*)(ap + kt * 32 + quad * 8);
                float4 f0 = p[0], f1 = p[1];
                union { ushort us[8]; short8 v; } cv;
                cv.us[0]=f2bf(f0.x); cv.us[1]=f2bf(f0.y); cv.us[2]=f2bf(f0.z); cv.us[3]=f2bf(f0.w);
                cv.us[4]=f2bf(f1.x); cv.us[5]=f2bf(f1.y); cv.us[6]=f2bf(f1.z); cv.us[7]=f2bf(f1.w);
                afrag[mt][kt] = cv.v;
            }
        } else {
            for (int kt = 0; kt < 4; kt++) afrag[mt][kt] = zf;
        }
    }
    __syncthreads();
    for (int nt = 0; nt < 8; nt++) {
        f32x4 acc0 = {0.f,0.f,0.f,0.f}, acc1 = {0.f,0.f,0.f,0.f};
        for (int kt = 0; kt < 4; kt++) {
            short8 b = *(const short8*)(&Bs[(nt * 16 + l16) * LDSTRIDE + kt * 32 + quad * 8]);
            acc0 = mfma_bf16(afrag[0][kt], b, acc0);
            acc1 = mfma_bf16(afrag[1][kt], b, acc1);
        }
        int colg = nt * 16 + l16;
        float bv = bias[colg];
        for (int r = 0; r < 4; r++) {
            int row0 = rowbase + quad * 4 + r;
            if (row0 < M) {
                float v = acc0[r] + bv; v = v > 0.f ? v : 0.f;
                Hout[(size_t)row0 * 128 + colg] = f2bf(v);
            }
            int row1 = rowbase + 16 + quad * 4 + r;
            if (row1 < M) {
                float v = acc1[r] + bv; v = v > 0.f ? v : 0.f;
                Hout[(size_t)row1 * 128 + colg] = f2bf(v);
            }
        }
    }
}

// ---- layer GEMM: [m | r | a_src | a_dst] = h @ [Wm | Wr | Wa_s | Wa_d] ----
__global__ __launch_bounds__(256) void k_gemm_layer(
    const ushort* __restrict__ Hin, const ushort* __restrict__ Bt,
    const float* __restrict__ bm, const float* __restrict__ br,
    ushort* __restrict__ Mout, float* __restrict__ Rout,
    float* __restrict__ asrc, float* __restrict__ adst, int M)
{
    __shared__ ushort Bs[NCOL_L * LDSTRIDE];
    int tid = threadIdx.x;
    for (int idx = tid; idx < NCOL_L * 16; idx += 256) {
        int col = idx >> 4, kk = (idx & 15) << 3;
        uint4 v = *(const uint4*)(Bt + col * 128 + kk);
        *(uint4*)(&Bs[col * LDSTRIDE + kk]) = v;
    }
    int wave = tid >> 6, lane = tid & 63, quad = lane >> 4, l16 = lane & 15;
    int rowbase = blockIdx.x * 128 + wave * 32;
    short8 zf = {0,0,0,0,0,0,0,0};
    short8 afrag[2][4];
    for (int mt = 0; mt < 2; mt++) {
        int row = rowbase + mt * 16 + l16;
        for (int kt = 0; kt < 4; kt++) {
            afrag[mt][kt] = (row < M)
                ? *(const short8*)(Hin + (size_t)row * 128 + kt * 32 + quad * 8) : zf;
        }
    }
    __syncthreads();
    for (int nt = 0; nt < 17; nt++) {
        f32x4 acc0 = {0.f,0.f,0.f,0.f}, acc1 = {0.f,0.f,0.f,0.f};
        for (int kt = 0; kt < 4; kt++) {
            short8 b = *(const short8*)(&Bs[(nt * 16 + l16) * LDSTRIDE + kt * 32 + quad * 8]);
            acc0 = mfma_bf16(afrag[0][kt], b, acc0);
            acc1 = mfma_bf16(afrag[1][kt], b, acc1);
        }
        int colg = nt * 16 + l16;
        for (int half = 0; half < 2; half++) {
            f32x4 acc = half ? acc1 : acc0;
            int rb = rowbase + half * 16 + quad * 4;
            for (int r = 0; r < 4; r++) {
                int row = rb + r;
                if (row >= M) continue;
                float v = acc[r];
                if (colg < 128) {
                    Mout[(size_t)row * 128 + colg] = f2bf(v + bm[colg]);
                } else if (colg < 256) {
                    Rout[(size_t)row * 128 + (colg - 128)] = v + br[colg - 128];
                } else if (colg == 256) {
                    asrc[row] = v;
                } else if (colg == 257) {
                    adst[row] = v;
                }
            }
        }
    }
}

// ------ aggregation: pre = seg_sum(gate*m[src]) + r (in place) + stats -----
// wave per 8 nodes. Per node: lanes 0..deg-1 load csrc (coalesced), gather
// asrc (parallel), compute sigmoid (parallel); then __shfl-broadcast (s,g)
// and issue 4 independent coalesced m-row loads per step. No serial
// load->load dependence remains.
__global__ __launch_bounds__(256) void k_agg(
    const int* __restrict__ offs, const int* __restrict__ csrc,
    const float* __restrict__ asrc, const float* __restrict__ adst,
    const float* __restrict__ ba, const ushort* __restrict__ Mb,
    float* __restrict__ pre, float* __restrict__ stats, int Nn)
{
    __shared__ float s_acc[256];   // [0..127] sum, [128..255] sumsq per feature
    int tid = threadIdx.x;
    s_acc[tid] = 0.f;
    __syncthreads();
    int wave = tid >> 6, lane = tid & 63;
    float bav = ba[0];
    int nbase = blockIdx.x * 32 + wave * 8;
    // lane-parallel prefetch of per-node metadata for all 8 nodes
    int offv = 0; float adv = 0.f;
    if (lane < 9) {
        int idx = nbase + lane; if (idx > Nn) idx = Nn;
        offv = offs[idx];
    }
    if (lane < 8) {
        int idx = nbase + lane;
        if (idx < Nn) adv = adst[idx] + bav;
    }
    float ps0 = 0, ps1 = 0, pq0 = 0, pq1 = 0;
    for (int ni = 0; ni < 8; ni++) {
        int node = nbase + ni;
        if (node >= Nn) break;
        int j0 = __shfl(offv, ni, 64);
        int j1 = __shfl(offv, ni + 1, 64);
        float ad = __shfl(adv, ni, 64);
        float2 rv = *(const float2*)(pre + (size_t)node * 128 + lane * 2);  // prefetch
        float a0 = 0.f, a1 = 0.f;
        for (int base = j0; base < j1; base += 64) {
            int cnt = j1 - base; if (cnt > 64) cnt = 64;
            int sv = 0; float gv = 0.f;
            if (lane < cnt) {
                sv = csrc[base + lane];
                float e = asrc[sv] + ad;
                gv = 1.f / (1.f + __expf(-e));
            }
            int i = 0;
            for (; i + 4 <= cnt; i += 4) {
                int s0 = __shfl(sv, i, 64),     s1 = __shfl(sv, i + 1, 64);
                int s2 = __shfl(sv, i + 2, 64), s3 = __shfl(sv, i + 3, 64);
                float g0 = __shfl(gv, i, 64),     g1 = __shfl(gv, i + 1, 64);
                float g2 = __shfl(gv, i + 2, 64), g3 = __shfl(gv, i + 3, 64);
                uint m0 = *(const uint*)(Mb + (size_t)s0 * 128 + lane * 2);
                uint m1 = *(const uint*)(Mb + (size_t)s1 * 128 + lane * 2);
                uint m2 = *(const uint*)(Mb + (size_t)s2 * 128 + lane * 2);
                uint m3 = *(const uint*)(Mb + (size_t)s3 * 128 + lane * 2);
                a0 += g0 * bflo(m0) + g1 * bflo(m1) + g2 * bflo(m2) + g3 * bflo(m3);
                a1 += g0 * bfhi(m0) + g1 * bfhi(m1) + g2 * bfhi(m2) + g3 * bfhi(m3);
            }
            for (; i < cnt; i++) {
                int s = __shfl(sv, i, 64);
                float g = __shfl(gv, i, 64);
                uint mm = *(const uint*)(Mb + (size_t)s * 128 + lane * 2);
                a0 += g * bflo(mm);
                a1 += g * bfhi(mm);
            }
        }
        float p0 = a0 + rv.x, p1 = a1 + rv.y;
        *(float2*)(pre + (size_t)node * 128 + lane * 2) = make_float2(p0, p1);
        ps0 += p0; ps1 += p1; pq0 += p0 * p0; pq1 += p1 * p1;
    }
    atomicAdd(&s_acc[lane * 2], ps0);
    atomicAdd(&s_acc[lane * 2 + 1], ps1);
    atomicAdd(&s_acc[128 + lane * 2], pq0);
    atomicAdd(&s_acc[128 + lane * 2 + 1], pq1);
    __syncthreads();
    atomicAdd(&stats[tid], s_acc[tid]);
}

// --------- norm: h = relu((pre-mu)*rsqrt(var+eps)*gamma+beta) -> bf16 ------
__global__ __launch_bounds__(256) void k_norm(
    const float* __restrict__ pre, const float* __restrict__ stats,
    const float* __restrict__ gamma, const float* __restrict__ beta,
    ushort* __restrict__ Hout, int Nn)
{
    int idx = blockIdx.x * 256 + threadIdx.x;
    int row = idx >> 5;
    int f = (idx & 31) << 2;
    if (row >= Nn) return;
    float invN = 1.f / (float)Nn;
    float4 p = *(const float4*)(pre + (size_t)row * 128 + f);
    float vs[4] = {p.x, p.y, p.z, p.w};
    ushort os[4];
    for (int c = 0; c < 4; c++) {
        int fc = f + c;
        float mu = stats[fc] * invN;
        float var = stats[128 + fc] * invN - mu * mu;
        float rs = rsqrtf(var + EPSN);
        float v = (vs[c] - mu) * rs * gamma[fc] + beta[fc];
        v = v > 0.f ? v : 0.f;
        os[c] = f2bf(v);
    }
    uint2 st;
    st.x = (uint)os[0] | ((uint)os[1] << 16);
    st.y = (uint)os[2] | ((uint)os[3] << 16);
    *(uint2*)(Hout + (size_t)row * 128 + f) = st;
}

// ---------- pool: block per graph, 4 waves stride rows, LDS reduce ---------
__global__ __launch_bounds__(256) void k_pool(
    const ushort* __restrict__ Hb, const int* __restrict__ gstart,
    float* __restrict__ pooled)
{
    __shared__ float sred[512];
    int g = blockIdx.x;
    int n0 = gstart[g], n1 = gstart[g + 1];
    int wave = threadIdx.x >> 6, lane = threadIdx.x & 63;
    float a0 = 0.f, a1 = 0.f;
    int n = n0 + wave;
    for (; n + 12 < n1; n += 16) {
        uint u0 = *(const uint*)(Hb + (size_t)n * 128 + lane * 2);
        uint u1 = *(const uint*)(Hb + (size_t)(n + 4) * 128 + lane * 2);
        uint u2 = *(const uint*)(Hb + (size_t)(n + 8) * 128 + lane * 2);
        uint u3 = *(const uint*)(Hb + (size_t)(n + 12) * 128 + lane * 2);
        a0 += bflo(u0) + bflo(u1) + bflo(u2) + bflo(u3);
        a1 += bfhi(u0) + bfhi(u1) + bfhi(u2) + bfhi(u3);
    }
    for (; n < n1; n += 4) {
        uint u = *(const uint*)(Hb + (size_t)n * 128 + lane * 2);
        a0 += bflo(u);
        a1 += bfhi(u);
    }
    sred[wave * 128 + lane * 2]     = a0;
    sred[wave * 128 + lane * 2 + 1] = a1;
    __syncthreads();
    if (threadIdx.x < 128) {
        float s = sred[threadIdx.x] + sred[128 + threadIdx.x]
                + sred[256 + threadIdx.x] + sred[384 + threadIdx.x];
        pooled[g * 128 + threadIdx.x] = s;
    }
}

// ----------------------- MLP head: block per graph -------------------------
__global__ __launch_bounds__(64) void k_mlp(
    const float* __restrict__ pooled, const float* __restrict__ W1, const float* __restrict__ b1,
    const float* __restrict__ W2, const float* __restrict__ b2, float* __restrict__ out)
{
    __shared__ float P[128];
    __shared__ float Hd[64];
    int g = blockIdx.x, j = threadIdx.x;
    P[j] = pooled[g * 128 + j];
    P[j + 64] = pooled[g * 128 + 64 + j];
    __syncthreads();
    float s0 = 0.f, s1 = 0.f, s2 = 0.f, s3 = 0.f;
    for (int k = 0; k < 128; k += 4) {
        s0 += P[k]     * W1[k * 64 + j];
        s1 += P[k + 1] * W1[(k + 1) * 64 + j];
        s2 += P[k + 2] * W1[(k + 2) * 64 + j];
        s3 += P[k + 3] * W1[(k + 3) * 64 + j];
    }
    float s = b1[j] + ((s0 + s1) + (s2 + s3));
    Hd[j] = s > 0.f ? s : 0.f;
    __syncthreads();
    if (j < 10) {
        float t0 = 0.f, t1 = 0.f;
        for (int k = 0; k < 64; k += 2) {
            t0 += Hd[k]     * W2[k * 10 + j];
            t1 += Hd[k + 1] * W2[(k + 1) * 10 + j];
        }
        out[g * 10 + j] = (b2[j] + t0 + t1) * 0.5f;   // / TEMP
    }
}

// ---------------------------------------------------------------------------
extern "C" void kernel_launch(void* const* d_in, const int* in_sizes, int n_in,
                              void* d_out, int out_size, void* d_ws, size_t ws_size,
                              hipStream_t stream)
{
    const float* x     = (const float*)d_in[0];
    const int*   ei    = (const int*)  d_in[1];
    const int*   batch = (const int*)  d_in[2];
    const float* W_in  = (const float*)d_in[3];
    const float* b_in  = (const float*)d_in[4];
    const float* Wa    = (const float*)d_in[5];
    const float* ba    = (const float*)d_in[6];
    const float* Wm    = (const float*)d_in[7];
    const float* bm    = (const float*)d_in[8];
    const float* Wr    = (const float*)d_in[9];
    const float* br    = (const float*)d_in[10];
    const float* gamma = (const float*)d_in[11];
    const float* beta  = (const float*)d_in[12];
    const float* W1    = (const float*)d_in[13];
    const float* b1    = (const float*)d_in[14];
    const float* W2    = (const float*)d_in[15];
    const float* b2    = (const float*)d_in[16];
    float* out = (float*)d_out;

    const int N = in_sizes[0] / 128;    // 50000
    const int E = in_sizes[1] / 2;      // 600000
    const int* e_src = ei;
    const int* e_dst = ei + E;

    // -------- workspace layout (bytes) --------
    char* ws = (char*)d_ws;
    ushort* h_b    = (ushort*)(ws + 0);               // 12,800,000  bf16 h
    ushort* m_b    = (ushort*)(ws + 12800000);        // 12,800,000  bf16 m
    float*  pre    = (float*) (ws + 25600000);        // 25,600,000  r/pre fp32
    float*  asrc   = (float*) (ws + 51200000);        //    200,000
    float*  adst   = (float*) (ws + 51400000);        //    200,000
    int*    counts = (int*)   (ws + 51600000);        //    200,000
    int*    cursor = (int*)   (ws + 51800000);        //    200,000
    int*    offs   = (int*)   (ws + 52000000);        //    200,064 (N+1)
    int*    csrc   = (int*)   (ws + 52200064);        //  2,400,000
    int*    bsums  = (int*)   (ws + 54600064);        //      1,024
    ushort* Btin   = (ushort*)(ws + 54601088);        //     32,768
    ushort* Btl    = (ushort*)(ws + 54633856);        //    278,528
    float*  stats  = (float*) (ws + 54912384);        //      4,096 (4 x 256)
    float*  pooled = (float*) (ws + 54916480);        //     32,768
    int*    gstart = (int*)   (ws + 54949248);        //        260 (G+1)
    (void)ws_size; (void)n_in; (void)out_size;

    hipMemsetAsync(counts, 0, 400000, stream);   // counts + cursor
    hipMemsetAsync(stats, 0, 4096, stream);      // stats only

    const int nbE = (E + 255) / 256;          // 2344
    const int nbN = (N + 255) / 256;          // 196
    const int nbG = (N + 127) / 128;          // 391 gemm blocks
    const int nbA = (N + 31) / 32;            // 1563 agg blocks
    const int nbNorm = (N * 32 + 255) / 256;  // 6250

    k_prep<<<608, 256, 0, stream>>>(W_in, Wa, Wm, Wr, Btin, Btl);
    k_hist<<<nbE, 256, 0, stream>>>(e_dst, counts, E);
    k_scan1<<<nbN, 256, 0, stream>>>(counts, offs, bsums, N);
    k_scan2<<<1, 256, 0, stream>>>(bsums, offs, nbN, N);
    k_scan3<<<nbN, 256, 0, stream>>>(offs, bsums, N);
    k_bucket<<<nbE, 256, 0, stream>>>(e_src, e_dst, offs, cursor, csrc, E);
    k_gbound<<<nbN, 256, 0, stream>>>(batch, gstart, N);

    k_gemm_in<<<nbG, 256, 0, stream>>>(x, Btin, b_in, h_b, N);

    for (int l = 0; l < 4; l++) {
        k_gemm_layer<<<nbG, 256, 0, stream>>>(h_b, Btl + l * (NCOL_L * 128),
                                              bm + l * 128, br + l * 128,
                                              m_b, pre, asrc, adst, N);
        k_agg<<<nbA, 256, 0, stream>>>(offs, csrc, asrc, adst, ba + l,
                                       m_b, pre, stats + l * 256, N);
        k_norm<<<nbNorm, 256, 0, stream>>>(pre, stats + l * 256,
                                           gamma + l * 128, beta + l * 128, h_b, N);
    }

    k_pool<<<NGRAPH, 256, 0, stream>>>(h_b, gstart, pooled);
    k_mlp<<<NGRAPH, 64, 0, stream>>>(pooled, W1, b1, W2, b2, out);
}